// Round 1
// baseline (681.659 us; speedup 1.0000x reference)
//
#include <hip/hip_runtime.h>

#define BB 64
#define SS 2048
#define DD 1024
#define SCHUNK 128
#define NC (SS / SCHUNK)   // 16 s-chunks

// Pass 1: per (b, s-chunk) partial masked/full sums over D.
__global__ __launch_bounds__(256) void ep_partial(
    const float* __restrict__ hidden, const int* __restrict__ mask,
    float* __restrict__ wsm, float* __restrict__ wsf)
{
    const int b = blockIdx.x;
    const int c = blockIdx.y;
    const int s0 = c * SCHUNK;

    __shared__ float smask[SCHUNK];
    for (int i = threadIdx.x; i < SCHUNK; i += 256)
        smask[i] = (float)mask[b * SS + s0 + i];
    __syncthreads();

    // thread t owns d = 4*t .. 4*t+3 (256 threads * 4 = D)
    const float4* hp = reinterpret_cast<const float4*>(
        hidden + ((size_t)b * SS + s0) * DD) + threadIdx.x;

    float4 am = make_float4(0.f, 0.f, 0.f, 0.f);
    float4 af = make_float4(0.f, 0.f, 0.f, 0.f);
    #pragma unroll 8
    for (int s = 0; s < SCHUNK; ++s) {
        float4 v = hp[(size_t)s * (DD / 4)];
        float  m = smask[s];              // same-address LDS broadcast, free
        af.x += v.x;     af.y += v.y;     af.z += v.z;     af.w += v.w;
        am.x += v.x * m; am.y += v.y * m; am.z += v.z * m; am.w += v.w * m;
    }

    const size_t o = (size_t)(b * NC + c) * (DD / 4) + threadIdx.x;
    reinterpret_cast<float4*>(wsm)[o] = am;
    reinterpret_cast<float4*>(wsf)[o] = af;
}

// Pass 2: reduce NC partials per batch, compute cnt, divide, store.
__global__ __launch_bounds__(256) void ep_finalize(
    const float* __restrict__ wsm, const float* __restrict__ wsf,
    const int* __restrict__ mask, float* __restrict__ out)
{
    const int b = blockIdx.x;

    __shared__ int s_cnt;
    if (threadIdx.x == 0) s_cnt = 0;
    __syncthreads();

    int local = 0;
    for (int s = threadIdx.x; s < SS; s += 256)
        local += mask[b * SS + s];
    #pragma unroll
    for (int off = 32; off > 0; off >>= 1)
        local += __shfl_down(local, off);      // wave = 64 lanes
    if ((threadIdx.x & 63) == 0) atomicAdd(&s_cnt, local);
    __syncthreads();
    const float cnt = (float)s_cnt;

    const float4* pm = reinterpret_cast<const float4*>(wsm)
                       + (size_t)b * NC * (DD / 4) + threadIdx.x;
    const float4* pf = reinterpret_cast<const float4*>(wsf)
                       + (size_t)b * NC * (DD / 4) + threadIdx.x;

    float4 am = make_float4(0.f, 0.f, 0.f, 0.f);
    float4 af = make_float4(0.f, 0.f, 0.f, 0.f);
    #pragma unroll
    for (int c = 0; c < NC; ++c) {
        float4 vm = pm[c * (DD / 4)];
        float4 vf = pf[c * (DD / 4)];
        am.x += vm.x; am.y += vm.y; am.z += vm.z; am.w += vm.w;
        af.x += vf.x; af.y += vf.y; af.z += vf.z; af.w += vf.w;
    }

    float4 r;
    if (cnt > 0.f) {
        r.x = am.x / cnt; r.y = am.y / cnt; r.z = am.z / cnt; r.w = am.w / cnt;
    } else {
        const float invS = 1.0f / (float)SS;
        r.x = af.x * invS; r.y = af.y * invS; r.z = af.z * invS; r.w = af.w * invS;
    }
    reinterpret_cast<float4*>(out)[(size_t)b * (DD / 4) + threadIdx.x] = r;
}

extern "C" void kernel_launch(void* const* d_in, const int* in_sizes, int n_in,
                              void* d_out, int out_size, void* d_ws, size_t ws_size,
                              hipStream_t stream) {
    const float* hidden = (const float*)d_in[0];
    const int*   mask   = (const int*)d_in[1];
    float*       out    = (float*)d_out;

    // workspace layout: [B*NC*D] masked partials | [B*NC*D] full partials (8 MiB)
    float* wsm = (float*)d_ws;
    float* wsf = wsm + (size_t)BB * NC * DD;

    dim3 grid1(BB, NC);
    ep_partial<<<grid1, 256, 0, stream>>>(hidden, mask, wsm, wsf);
    ep_finalize<<<BB, 256, 0, stream>>>(wsm, wsf, mask, out);
}